// Round 5
// baseline (369.677 us; speedup 1.0000x reference)
//
#include <hip/hip_runtime.h>
#include <cstdint>

// Problem constants (B,D,H,W,C = 4,8,16,16,512; R = 64; F = H*W = 256)
// INPUTS: float32 (per reference setup_inputs). OUTPUT: float32 (reference returns f32).
#define BB 4
#define DD 8
#define FF 256
#define CC 512
#define RR_ 64
#define NROW 8192      // BB*DD*FF
#define NKEY 2048      // DD*FF (keys per batch)
#define LN_EPS 1e-3f

__device__ __forceinline__ float lo16(uint32_t u){ union{uint32_t x;float f;}c; c.x = u<<16; return c.f; }
__device__ __forceinline__ float hi16(uint32_t u){ union{uint32_t x;float f;}c; c.x = u & 0xffff0000u; return c.f; }
__device__ __forceinline__ uint32_t pack_bf16(float a, float b){
    union{float f;uint32_t u;} ca, cb; ca.f = a; cb.f = b;
    uint32_t ua = ca.u + (0x7fffu + ((ca.u>>16)&1u));   // RNE
    uint32_t ub = cb.u + (0x7fffu + ((cb.u>>16)&1u));
    return (ua>>16) | (ub & 0xffff0000u);
}
__device__ __forceinline__ void dot4(float& s, float4 a, float4 b){
    s = fmaf(a.x,b.x,s); s = fmaf(a.y,b.y,s); s = fmaf(a.z,b.z,s); s = fmaf(a.w,b.w,s);
}

// ---------------- K1: Q/K projection (f32 in, bf16-packed out to ws) ----------------
// grid 512 (16 rows each), block 256. Threads 0-127: Q, 128-255: K.
// Within each half: pair-col L = u&31 (cols 2L,2L+1), row group rg = u>>5 (rows rg*4..+3).
__global__ __launch_bounds__(256) void k1_qk(
    const float* __restrict__ x,
    const float* __restrict__ wq, const float* __restrict__ bq,
    const float* __restrict__ wk, const float* __restrict__ bk,
    uint32_t* __restrict__ Qh, uint32_t* __restrict__ Kh)
{
    __shared__ float xs[16][CC];
    const int t = threadIdx.x;
    const int rowbase = blockIdx.x << 4;
    {   // stage x tile 16x512 f32 (2048 float4)
        const float4* xp = (const float4*)(x + (size_t)rowbase * CC);
        #pragma unroll
        for (int i = 0; i < 8; ++i) {
            int idx = t + (i<<8);            // 0..2047
            int row = idx >> 7;              // 128 float4 per row
            int col = (idx & 127) << 2;
            *(float4*)&xs[row][col] = xp[idx];
        }
    }
    __syncthreads();

    const bool isQ = (t < 128);
    const int u  = t & 127;
    const int L  = u & 31;        // pair column (2L,2L+1)
    const int rg = u >> 5;        // row group 0..3
    const float* wp = (isQ ? wq : wk) + 2*L;
    float a0[4], a1[4];
    #pragma unroll
    for (int i=0;i<4;++i){ a0[i]=0.f; a1[i]=0.f; }
    for (int r4 = 0; r4 < 128; ++r4) {
        float2 w0 = *(const float2*)(wp + (size_t)(r4*4+0)*RR_);
        float2 w1 = *(const float2*)(wp + (size_t)(r4*4+1)*RR_);
        float2 w2 = *(const float2*)(wp + (size_t)(r4*4+2)*RR_);
        float2 w3 = *(const float2*)(wp + (size_t)(r4*4+3)*RR_);
        #pragma unroll
        for (int i = 0; i < 4; ++i) {
            float4 xv = *(const float4*)&xs[rg*4+i][r4*4];
            a0[i]=fmaf(xv.x,w0.x,a0[i]); a1[i]=fmaf(xv.x,w0.y,a1[i]);
            a0[i]=fmaf(xv.y,w1.x,a0[i]); a1[i]=fmaf(xv.y,w1.y,a1[i]);
            a0[i]=fmaf(xv.z,w2.x,a0[i]); a1[i]=fmaf(xv.z,w2.y,a1[i]);
            a0[i]=fmaf(xv.w,w3.x,a0[i]); a1[i]=fmaf(xv.w,w3.y,a1[i]);
        }
    }
    float2 bb = *(const float2*)((isQ ? bq : bk) + 2*L);
    uint32_t* dst = isQ ? Qh : Kh;
    #pragma unroll
    for (int i=0;i<4;++i)
        dst[(size_t)(rowbase + rg*4 + i)*32 + L] = pack_bf16(a0[i]+bb.x, a1[i]+bb.y);
}

// ---------------- K23: scores + softmax + g-fold + attn + residual + LN -> y1 (f32) -------
// attn = a2 @ V = (a2 @ x_bd) @ wv + bv   (sum_j a2 = 1 absorbs the bias)
// grid 512 = (b, d, f-tile of 16 queries), block 256.
// Phase A: thread owns 2 queries (qt=t>>5) x 4 keys (kq*32+(t&31)) per 128-key chunk;
//   plain exp (score std ~1.6, max ~9 -> f32-safe), accumulate a2 + l in regs.
// Phase B: z = a2 @ x_bd (16x512), thread owns cols (2t,2t+1).
// Phase C: attn = z @ wv + bv; residual + LayerNorm -> d_out rows (f32).
__global__ __launch_bounds__(256) void k23_attn_ln(
    const uint32_t* __restrict__ Qh, const uint32_t* __restrict__ Kh,
    const float* __restrict__ x, const float* __restrict__ wv, const float* __restrict__ bv,
    const float* __restrict__ g1, const float* __restrict__ b1,
    float* __restrict__ Y1)
{
    __shared__ float qs[16][68];
    __shared__ float pool[128*68];      // phase A: ks[128][68]; phase B/C: zs[16][512]
    __shared__ float as2[16][FF];
    __shared__ float reds[16][4], redq[16][4];
    const int t = threadIdx.x;
    const int b   = blockIdx.x >> 7;
    const int rem = blockIdx.x & 127;
    const int d   = rem >> 4;
    const int ft  = rem & 15;
    const int bd  = b*DD + d;
    const int rowbase = (bd << 8) + (ft << 4);
    const uint32_t* Kb = Kh + (size_t)b * NKEY * 32;

    {   // load Q tile 16x64 (bf16-packed): thread t loads dwords cd,cd+1 of row t>>4
        int row = t >> 4;
        int cd  = (t & 15) * 2;
        const uint32_t* Qr = Qh + (size_t)(rowbase+row)*32 + cd;
        uint32_t u0 = Qr[0], u1 = Qr[1];
        float4 v; v.x=lo16(u0); v.y=hi16(u0); v.z=lo16(u1); v.w=hi16(u1);
        *(float4*)&qs[row][cd*2] = v;
    }

    const int qt = t >> 5;   // 0..7 (query pair index; 32 lanes share it)
    const int kt = t & 31;
    float l[2] = {0.f, 0.f};
    float a2acc[2][8];
    #pragma unroll
    for (int i=0;i<2;++i){ for (int j=0;j<8;++j) a2acc[i][j]=0.f; }

    for (int cc = 0; cc < 16; ++cc) {
        __syncthreads();
        {   // stage 128 key rows (bf16-packed -> f32), stride 68
            const uint4* src = (const uint4*)(Kb + (size_t)cc*128*32);
            #pragma unroll
            for (int i=0;i<4;++i){
                int idx = t + (i<<8);             // 0..1023
                int row = idx >> 3;               // 8 uint4 per row
                int c8  = (idx & 7) << 3;
                uint4 u = src[idx];
                float* dst = &pool[row*68 + c8];
                dst[0]=lo16(u.x); dst[1]=hi16(u.x); dst[2]=lo16(u.y); dst[3]=hi16(u.y);
                dst[4]=lo16(u.z); dst[5]=hi16(u.z); dst[6]=lo16(u.w); dst[7]=hi16(u.w);
            }
        }
        __syncthreads();
        float s[2][4];
        #pragma unroll
        for (int i=0;i<2;++i){ for(int j=0;j<4;++j) s[i][j]=0.f; }
        for (int r4 = 0; r4 < 16; ++r4){
            float4 qv0 = *(const float4*)&qs[qt*2+0][r4*4];
            float4 qv1 = *(const float4*)&qs[qt*2+1][r4*4];
            float4 kv0 = *(const float4*)&pool[( 0+kt)*68 + r4*4];
            float4 kv1 = *(const float4*)&pool[(32+kt)*68 + r4*4];
            float4 kv2 = *(const float4*)&pool[(64+kt)*68 + r4*4];
            float4 kv3 = *(const float4*)&pool[(96+kt)*68 + r4*4];
            dot4(s[0][0],qv0,kv0); dot4(s[0][1],qv0,kv1); dot4(s[0][2],qv0,kv2); dot4(s[0][3],qv0,kv3);
            dot4(s[1][0],qv1,kv0); dot4(s[1][1],qv1,kv1); dot4(s[1][2],qv1,kv2); dot4(s[1][3],qv1,kv3);
        }
        const int par = cc & 1;   // key j = par*128 + kq*32 + kt
        #pragma unroll
        for (int qq=0; qq<2; ++qq){
            float e0 = __expf(s[qq][0]);
            float e1 = __expf(s[qq][1]);
            float e2 = __expf(s[qq][2]);
            float e3 = __expf(s[qq][3]);
            l[qq] += (e0+e1) + (e2+e3);
            float* ac = &a2acc[qq][par*4];
            ac[0]+=e0; ac[1]+=e1; ac[2]+=e2; ac[3]+=e3;
        }
    }
    // sum l across the 32 lanes owning each query; write normalized a2 to LDS
    #pragma unroll
    for (int qq=0; qq<2; ++qq){
        float ll = l[qq];
        #pragma unroll
        for (int off=1; off<32; off<<=1) ll += __shfl_xor(ll, off, 64);
        float fac = 1.f / ll;
        const int row = qt*2 + qq;
        #pragma unroll
        for (int p=0;p<2;++p)
            #pragma unroll
            for (int kq=0;kq<4;++kq)
                as2[row][p*128 + kq*32 + kt] = a2acc[qq][p*4+kq] * fac;
    }
    __syncthreads();   // as2 visible; pool (ks) dead from here

    // ---- Phase B: z = a2 @ x_bd  (16x256 @ 256x512), thread owns cols (2t,2t+1)
    float z0[16], z1[16];
    #pragma unroll
    for (int i=0;i<16;++i){ z0[i]=0.f; z1[i]=0.f; }
    const float* xb = x + ((size_t)bd << 8) * CC;  // 256 rows x 512 f32
    for (int j4 = 0; j4 < 64; ++j4) {
        float2 v0 = *(const float2*)(xb + (size_t)(j4*4+0)*CC + 2*t);
        float2 v1 = *(const float2*)(xb + (size_t)(j4*4+1)*CC + 2*t);
        float2 v2 = *(const float2*)(xb + (size_t)(j4*4+2)*CC + 2*t);
        float2 v3 = *(const float2*)(xb + (size_t)(j4*4+3)*CC + 2*t);
        #pragma unroll
        for (int rr=0;rr<16;++rr){
            float4 av = *(const float4*)&as2[rr][j4*4];
            z0[rr]=fmaf(av.x,v0.x,z0[rr]); z1[rr]=fmaf(av.x,v0.y,z1[rr]);
            z0[rr]=fmaf(av.y,v1.x,z0[rr]); z1[rr]=fmaf(av.y,v1.y,z1[rr]);
            z0[rr]=fmaf(av.z,v2.x,z0[rr]); z1[rr]=fmaf(av.z,v2.y,z1[rr]);
            z0[rr]=fmaf(av.w,v3.x,z0[rr]); z1[rr]=fmaf(av.w,v3.y,z1[rr]);
        }
    }
    {   // stash z into pool as zs[16][512]
        #pragma unroll
        for (int rr=0;rr<16;++rr){
            float2 v; v.x = z0[rr]; v.y = z1[rr];
            *(float2*)&pool[rr*512 + 2*t] = v;
        }
    }
    __syncthreads();

    // ---- Phase C: attn = zs @ wv + bv; residual; LayerNorm
    float at0[16], at1[16];
    #pragma unroll
    for (int i=0;i<16;++i){ at0[i]=0.f; at1[i]=0.f; }
    const float* wvp = wv + 2*t;
    for (int r4 = 0; r4 < 128; ++r4) {
        float2 w0 = *(const float2*)(wvp + (size_t)(r4*4+0)*CC);
        float2 w1 = *(const float2*)(wvp + (size_t)(r4*4+1)*CC);
        float2 w2 = *(const float2*)(wvp + (size_t)(r4*4+2)*CC);
        float2 w3 = *(const float2*)(wvp + (size_t)(r4*4+3)*CC);
        #pragma unroll
        for (int rr=0;rr<16;++rr){
            float4 zv = *(const float4*)&pool[rr*512 + r4*4];   // broadcast
            at0[rr]=fmaf(zv.x,w0.x,at0[rr]); at1[rr]=fmaf(zv.x,w0.y,at1[rr]);
            at0[rr]=fmaf(zv.y,w1.x,at0[rr]); at1[rr]=fmaf(zv.y,w1.y,at1[rr]);
            at0[rr]=fmaf(zv.z,w2.x,at0[rr]); at1[rr]=fmaf(zv.z,w2.y,at1[rr]);
            at0[rr]=fmaf(zv.w,w3.x,at0[rr]); at1[rr]=fmaf(zv.w,w3.y,at1[rr]);
        }
    }
    float2 bvv = *(const float2*)(bv + 2*t);
    const int wvi = t >> 6, lane = t & 63;
    #pragma unroll
    for (int rr=0;rr<16;++rr){
        float2 xr = *(const float2*)(x + (size_t)(rowbase+rr)*CC + 2*t);
        float zz0 = at0[rr] + bvv.x + xr.x;
        float zz1 = at1[rr] + bvv.y + xr.y;
        at0[rr]=zz0; at1[rr]=zz1;
        float sv = zz0+zz1, qv = fmaf(zz0,zz0, zz1*zz1);
        #pragma unroll
        for (int off=32; off>0; off>>=1){
            sv += __shfl_down(sv, off, 64);
            qv += __shfl_down(qv, off, 64);
        }
        if (lane==0){ reds[rr][wvi]=sv; redq[rr][wvi]=qv; }
    }
    __syncthreads();
    float2 gg = *(const float2*)(g1 + 2*t);
    float2 bb = *(const float2*)(b1 + 2*t);
    #pragma unroll
    for (int rr=0;rr<16;++rr){
        float sv = reds[rr][0]+reds[rr][1]+reds[rr][2]+reds[rr][3];
        float qv = redq[rr][0]+redq[rr][1]+redq[rr][2]+redq[rr][3];
        float mean = sv * (1.f/CC);
        float var  = qv * (1.f/CC) - mean*mean;
        float rstd = rsqrtf(var + LN_EPS);
        float2 yv;
        yv.x = (at0[rr]-mean)*rstd*gg.x + bb.x;
        yv.y = (at1[rr]-mean)*rstd*gg.y + bb.y;
        *(float2*)&Y1[(size_t)(rowbase+rr)*CC + 2*t] = yv;
    }
}

// ---------------- K4: MLP (relu(y1@wm+bm)) + residual + LayerNorm, IN-PLACE on d_out (f32) --
// Safe in-place: each block fully reads its 16 rows into LDS before writing them.
__global__ __launch_bounds__(256) void k4_mlp_ln(
    float* io, const float* __restrict__ wm, const float* __restrict__ bm,
    const float* __restrict__ g2, const float* __restrict__ b2)
{
    __shared__ float ys[16][CC];
    __shared__ float reds[16][4], redq[16][4];
    const int t = threadIdx.x;
    const int rowbase = blockIdx.x << 4;
    {   // y1 tile f32 -> LDS (4096 float2)
        const float2* src = (const float2*)(io + (size_t)rowbase*CC);
        #pragma unroll
        for (int i=0;i<16;++i){
            int idx = t + (i<<8);
            int row = idx >> 8, cp = idx & 255;    // 256 float2 per row
            float2 v = src[idx];
            *(float2*)&ys[row][cp*2] = v;
        }
    }
    __syncthreads();
    float acc0[16], acc1[16];
    #pragma unroll
    for (int i=0;i<16;++i){acc0[i]=0.f;acc1[i]=0.f;}
    const float* wmp = wm + 2*t;
    for (int r4=0;r4<128;++r4){
        float2 w0 = *(const float2*)(wmp + (size_t)(r4*4+0)*CC);
        float2 w1 = *(const float2*)(wmp + (size_t)(r4*4+1)*CC);
        float2 w2 = *(const float2*)(wmp + (size_t)(r4*4+2)*CC);
        float2 w3 = *(const float2*)(wmp + (size_t)(r4*4+3)*CC);
        #pragma unroll
        for (int rr=0;rr<16;++rr){
            float4 yv = *(const float4*)&ys[rr][r4*4];
            acc0[rr]=fmaf(yv.x,w0.x,acc0[rr]); acc1[rr]=fmaf(yv.x,w0.y,acc1[rr]);
            acc0[rr]=fmaf(yv.y,w1.x,acc0[rr]); acc1[rr]=fmaf(yv.y,w1.y,acc1[rr]);
            acc0[rr]=fmaf(yv.z,w2.x,acc0[rr]); acc1[rr]=fmaf(yv.z,w2.y,acc1[rr]);
            acc0[rr]=fmaf(yv.w,w3.x,acc0[rr]); acc1[rr]=fmaf(yv.w,w3.y,acc1[rr]);
        }
    }
    float2 bmv = *(const float2*)(bm + 2*t);
    const int wvi=t>>6, lane=t&63;
    #pragma unroll
    for (int rr=0;rr<16;++rr){
        float h0 = fmaxf(acc0[rr]+bmv.x, 0.f) + ys[rr][2*t];
        float h1 = fmaxf(acc1[rr]+bmv.y, 0.f) + ys[rr][2*t+1];
        acc0[rr]=h0; acc1[rr]=h1;
        float sv=h0+h1, qv=fmaf(h0,h0,h1*h1);
        #pragma unroll
        for (int off=32;off>0;off>>=1){
            sv += __shfl_down(sv,off,64);
            qv += __shfl_down(qv,off,64);
        }
        if (lane==0){reds[rr][wvi]=sv; redq[rr][wvi]=qv;}
    }
    __syncthreads();
    float2 gg = *(const float2*)(g2 + 2*t);
    float2 bb = *(const float2*)(b2 + 2*t);
    #pragma unroll
    for (int rr=0;rr<16;++rr){
        float sv=reds[rr][0]+reds[rr][1]+reds[rr][2]+reds[rr][3];
        float qv=redq[rr][0]+redq[rr][1]+redq[rr][2]+redq[rr][3];
        float mean = sv*(1.f/CC);
        float var  = qv*(1.f/CC) - mean*mean;
        float rstd = rsqrtf(var + LN_EPS);
        float2 yv;
        yv.x = (acc0[rr]-mean)*rstd*gg.x + bb.x;
        yv.y = (acc1[rr]-mean)*rstd*gg.y + bb.y;
        *(float2*)&io[(size_t)(rowbase+rr)*CC + 2*t] = yv;
    }
}

extern "C" void kernel_launch(void* const* d_in, const int* in_sizes, int n_in,
                              void* d_out, int out_size, void* d_ws, size_t ws_size,
                              hipStream_t stream) {
    (void)in_sizes; (void)n_in; (void)out_size; (void)ws_size;
    const float* x  = (const float*)d_in[0];
    const float* wq = (const float*)d_in[1];
    const float* bq = (const float*)d_in[2];
    const float* wk = (const float*)d_in[3];
    const float* bk = (const float*)d_in[4];
    const float* wv = (const float*)d_in[5];
    const float* bv = (const float*)d_in[6];
    const float* wm = (const float*)d_in[7];
    const float* bm = (const float*)d_in[8];
    const float* g1 = (const float*)d_in[9];
    const float* b1 = (const float*)d_in[10];
    const float* g2 = (const float*)d_in[11];
    const float* b2 = (const float*)d_in[12];

    // ws usage: 2 MB only.
    //   Qh @ 0      (8192 x 32 dwords bf16-packed, 1 MB)
    //   Kh @ 1 MB   (1 MB)
    // No V / A2 buffers: attn = (a2 @ x) @ wv + bv, all staged in LDS inside k23.
    // d_out: 4,194,304 f32 (16 MB) — y1 written there by k23, k4 runs in place.
    float* outp = (float*)d_out;
    uint32_t* Qh = (uint32_t*)d_ws;
    uint32_t* Kh = Qh + (size_t)NROW*32;

    k1_qk      <<<512, 256, 0, stream>>>(x, wq, bq, wk, bk, Qh, Kh);
    k23_attn_ln<<<512, 256, 0, stream>>>(Qh, Kh, x, wv, bv, g1, b1, outp);
    k4_mlp_ln  <<<512, 256, 0, stream>>>(outp, wm, bm, g2, b2);
}

// Round 6
// 164.622 us; speedup vs baseline: 2.2456x; 2.2456x over previous
//
#include <hip/hip_runtime.h>
#include <cstdint>

// B,D,H,W,C = 4,8,16,16,512; R=64; F=256; rows=8192; keys/batch=2048.
// Inputs f32; output f32. All GEMMs via mfma_f32_16x16x32_bf16 with
// fragment-ordered LDS panels: [n-tile][quad][c][8 k] (2-way bank conflicts only).
#define LN_EPS 1e-3f
using u16 = unsigned short;
using u32 = unsigned int;
typedef __attribute__((ext_vector_type(8))) short bh8;   // 8 bf16 (4 VGPRs)
typedef __attribute__((ext_vector_type(4))) float f4;    // 4 f32 acc
#define MFMA16(A,B,C) __builtin_amdgcn_mfma_f32_16x16x32_bf16((A),(B),(C),0,0,0)

__device__ __forceinline__ u16 bf16r(float f){
    union{float f;u32 u;} c; c.f=f;
    return (u16)((c.u + 0x7fffu + ((c.u>>16)&1u))>>16);
}
__device__ __forceinline__ u32 pk2(float a, float b){
    return (u32)bf16r(a) | ((u32)bf16r(b)<<16);
}
__device__ __forceinline__ void glds16(const void* g, void* l){
    __builtin_amdgcn_global_load_lds(
        (const __attribute__((address_space(1))) u32*)g,
        (__attribute__((address_space(3))) u32*)l, 16, 0, 0);
}

// ---------------- K0: repack f32 -> bf16 frag-ordered K-panels ----------------
// Panel element [s][nt][quad][c][j] = W[k = s*32+quad*8+j][n = nt*16+c].
// blocks 0..255: x panels per (bd,s8)  (B-operand of phase B, K-dim = key)
// blocks 256..271: wv ; 272..287: wm ; 288..303: wq||wk (N=128)
__global__ __launch_bounds__(256) void k0_prep(
    const float* __restrict__ x,  const float* __restrict__ wq, const float* __restrict__ wk,
    const float* __restrict__ wv, const float* __restrict__ wm,
    u16* __restrict__ x_pB, u16* __restrict__ wv_p, u16* __restrict__ wm_p, u16* __restrict__ wqk_p)
{
    const int t = threadIdx.x;
    const int c = t & 15, qn = t >> 4;
    const int quad = qn & 3, ntl = qn >> 2;
    const int blk = blockIdx.x;
    if (blk < 256){
        const int bd = blk >> 3, s = blk & 7;
        const float* src = x + ((size_t)(bd*256 + s*32 + quad*8))*512;
        u16* dst = x_pB + (size_t)(bd*8+s)*16384;
        #pragma unroll
        for (int i=0;i<8;++i){
            int nt = i*4 + ntl, n = nt*16 + c;
            float v[8];
            #pragma unroll
            for (int j=0;j<8;++j) v[j] = src[(size_t)j*512 + n];
            uint4 o; o.x=pk2(v[0],v[1]); o.y=pk2(v[2],v[3]); o.z=pk2(v[4],v[5]); o.w=pk2(v[6],v[7]);
            *(uint4*)&dst[((nt*4+quad)*16 + c)*8] = o;
        }
    } else if (blk < 288){
        const int ism = (blk >= 272);
        const int s = ism ? (blk-272) : (blk-256);
        const float* src = (ism ? wm : wv) + (size_t)(s*32 + quad*8)*512;
        u16* dst = (ism ? wm_p : wv_p) + (size_t)s*16384;
        #pragma unroll
        for (int i=0;i<8;++i){
            int nt = i*4 + ntl, n = nt*16 + c;
            float v[8];
            #pragma unroll
            for (int j=0;j<8;++j) v[j] = src[(size_t)j*512 + n];
            uint4 o; o.x=pk2(v[0],v[1]); o.y=pk2(v[2],v[3]); o.z=pk2(v[4],v[5]); o.w=pk2(v[6],v[7]);
            *(uint4*)&dst[((nt*4+quad)*16 + c)*8] = o;
        }
    } else {
        const int s = blk - 288;
        u16* dst = wqk_p + (size_t)s*4096;
        #pragma unroll
        for (int i=0;i<2;++i){
            int nt = i*4 + ntl, n = nt*16 + c;
            const float* src = (n < 64) ? (wq + (size_t)(s*32 + quad*8)*64 + n)
                                        : (wk + (size_t)(s*32 + quad*8)*64 + (n-64));
            float v[8];
            #pragma unroll
            for (int j=0;j<8;++j) v[j] = src[(size_t)j*64];
            uint4 o; o.x=pk2(v[0],v[1]); o.y=pk2(v[2],v[3]); o.z=pk2(v[4],v[5]); o.w=pk2(v[6],v[7]);
            *(uint4*)&dst[((nt*4+quad)*16 + c)*8] = o;
        }
    }
}

// ---------------- K1: Q/K projection (MFMA, N=128 = wq||wk) ----------------
// grid 512 (16 rows/block). Wave w covers cols w*32..+31. Output frag-ordered Qb/Kb:
// element [rt][kh][quad][c][j]: row = rt*16+c, r-dim = kh*32+quad*8+j.
__global__ __launch_bounds__(256) void k1_qk(
    const float* __restrict__ x, const float* __restrict__ bq, const float* __restrict__ bk,
    const u16* __restrict__ wqk_p, u16* __restrict__ Qb, u16* __restrict__ Kb)
{
    __shared__ u16 Asf[512];     // A-tile 16x32, frag order [quad][c][8]
    __shared__ u16 Bsf[4096];    // B-panel 32x128, 8 KB
    const int t = threadIdx.x, w = t>>6, lane = t&63, quad = lane>>4, c = lane&15;
    const int rowbase = blockIdx.x << 4;
    f4 acc[2] = { {0.f,0.f,0.f,0.f}, {0.f,0.f,0.f,0.f} };
    for (int s=0;s<16;++s){
        if (s) __syncthreads();
        if (t < 128){
            int fr = t>>3, fc = t&7;
            float4 xv = *(const float4*)&x[(size_t)(rowbase+fr)*512 + s*32 + fc*4];
            uint2 pkv; pkv.x = pk2(xv.x,xv.y); pkv.y = pk2(xv.z,xv.w);
            *(uint2*)&Asf[((fc>>1)*16 + fr)*8 + (fc&1)*4] = pkv;
        }
        #pragma unroll
        for (int i=0;i<2;++i){
            int ch = w*2 + i;
            glds16((const char*)wqk_p + (size_t)s*8192 + ch*1024 + lane*16, (char*)Bsf + ch*1024);
        }
        __syncthreads();
        bh8 a = *(const bh8*)&Asf[(quad*16+c)*8];
        #pragma unroll
        for (int nt=0;nt<2;++nt){
            bh8 b = *(const bh8*)&Bsf[((w*2+nt)*4 + quad)*128 + c*8];
            acc[nt] = MFMA16(a, b, acc[nt]);
        }
    }
    const int rt = blockIdx.x;
    #pragma unroll
    for (int nt=0;nt<2;++nt){
        int cqk = w*32 + nt*16 + c;
        bool isQ = (cqk < 64);
        int r = isQ ? cqk : (cqk - 64);
        float bias = isQ ? bq[r] : bk[r];
        int kh = r>>5, q2 = (r>>3)&3, j = r&7;
        u16* dstb = (isQ ? Qb : Kb) + (size_t)((rt*2 + kh)*4 + q2)*128 + j;
        #pragma unroll
        for (int reg=0;reg<4;++reg){
            int cp = quad*4 + reg;   // row within tile
            dstb[cp*8] = bf16r(acc[nt][reg] + bias);
        }
    }
}

// ---------------- K23: scores+softmax+g-fold+attn+residual+LN (all MFMA) ----------------
// attn = (a2 @ x_bd) @ wv + bv  (sum_j a2 = 1). grid 512 = (b,d,ft16), block 256.
__global__ __launch_bounds__(256) void k23_attn_ln(
    const u16* __restrict__ Qb, const u16* __restrict__ Kb,
    const u16* __restrict__ x_pB, const u16* __restrict__ wv_p,
    const float* __restrict__ x, const float* __restrict__ bv,
    const float* __restrict__ g1, const float* __restrict__ b1,
    float* __restrict__ Y1)
{
    __shared__ u16 Bs[16384];    // 32 KB: K-chunks (16 KB) / x panels / wv panels
    __shared__ u16 zsf[8192];    // z 16x512 frag-order [16 s][quad][c][8]
    __shared__ u16 a2f[4096];    // a2 16x256 frag-order [8 s][quad][c][8]
    __shared__ u16 qsf[1024];    // Q 16x64 frag-order [2 kh][quad][c][8]
    __shared__ float redA[4][16], redB[4][16];
    const int t = threadIdx.x, w = t>>6, lane = t&63, quad = lane>>4, c = lane&15;
    const int b = blockIdx.x >> 7, rem = blockIdx.x & 127, d = rem >> 4, ft = rem & 15;
    const int bd = b*8 + d;
    const int rowbase = (bd<<8) + (ft<<4);
    const int rt = rowbase >> 4;

    if (w < 2) glds16((const char*)Qb + (size_t)rt*2048 + w*1024 + lane*16, (char*)qsf + w*1024);

    float lp[4] = {0.f,0.f,0.f,0.f};
    float a2r[4][2][2];
    #pragma unroll
    for (int r=0;r<4;++r){ a2r[r][0][0]=0.f; a2r[r][0][1]=0.f; a2r[r][1][0]=0.f; a2r[r][1][1]=0.f; }

    __syncthreads();
    bh8 aq0 = *(const bh8*)&qsf[(quad*16+c)*8];
    bh8 aq1 = *(const bh8*)&qsf[512 + (quad*16+c)*8];

    // ---- Phase A: scores + exp + g-fold
    const char* Kbase = (const char*)Kb + (size_t)b*262144;
    for (int cc=0; cc<16; ++cc){
        if (cc) __syncthreads();
        #pragma unroll
        for (int i=0;i<4;++i){
            int ch = w*4 + i;
            glds16(Kbase + (size_t)cc*16384 + ch*1024 + lane*16, (char*)Bs + ch*1024);
        }
        __syncthreads();
        f4 sa[2] = { {0.f,0.f,0.f,0.f}, {0.f,0.f,0.f,0.f} };
        #pragma unroll
        for (int kt=0;kt<2;++kt){
            int tw = w*2 + kt;
            bh8 b0 = *(const bh8*)&Bs[tw*1024 +       (quad*16+c)*8];
            bh8 b1v= *(const bh8*)&Bs[tw*1024 + 512 + (quad*16+c)*8];
            sa[kt] = MFMA16(aq0, b0, sa[kt]);
            sa[kt] = MFMA16(aq1, b1v, sa[kt]);
        }
        const int h = cc & 1;
        #pragma unroll
        for (int kt=0;kt<2;++kt)
            #pragma unroll
            for (int reg=0;reg<4;++reg){
                float e = __expf(sa[kt][reg]);
                lp[reg] += e;
                a2r[reg][h][kt] += e;
            }
    }
    // softmax denominator: reduce over c-lanes, then waves
    #pragma unroll
    for (int reg=0;reg<4;++reg){
        float v = lp[reg];
        v += __shfl_xor(v,1,64); v += __shfl_xor(v,2,64);
        v += __shfl_xor(v,4,64); v += __shfl_xor(v,8,64);
        lp[reg] = v;
    }
    if (c==0){
        #pragma unroll
        for (int reg=0;reg<4;++reg) redA[w][quad*4+reg] = lp[reg];
    }
    __syncthreads();
    float fac[4];
    #pragma unroll
    for (int reg=0;reg<4;++reg){
        int q = quad*4+reg;
        fac[reg] = 1.f/(redA[0][q]+redA[1][q]+redA[2][q]+redA[3][q]);
    }
    // write normalized a2 in A-frag order: element (q, j): s'=j>>5, quad'=(j>>3)&3, jj=j&7
    #pragma unroll
    for (int reg=0;reg<4;++reg){
        int q = quad*4+reg;
        #pragma unroll
        for (int h=0;h<2;++h)
            #pragma unroll
            for (int kt=0;kt<2;++kt){
                int j = h*128 + (w*2+kt)*16 + c;
                a2f[(j>>5)*512 + (((j>>3)&3)*16 + q)*8 + (j&7)] = bf16r(a2r[reg][h][kt]*fac[reg]);
            }
    }
    __syncthreads();

    // ---- Phase B: z = a2 @ x_bd  (K=256, 8 steps)
    f4 zacc[8];
    #pragma unroll
    for (int nt=0;nt<8;++nt) zacc[nt] = (f4){0.f,0.f,0.f,0.f};
    const char* xpb = (const char*)x_pB + (size_t)bd*262144;
    for (int s=0;s<8;++s){
        if (s) __syncthreads();
        #pragma unroll
        for (int i=0;i<8;++i){
            int ch = w*8 + i;
            glds16(xpb + (size_t)s*32768 + ch*1024 + lane*16, (char*)Bs + ch*1024);
        }
        __syncthreads();
        bh8 a = *(const bh8*)&a2f[s*512 + (quad*16+c)*8];
        #pragma unroll
        for (int nt=0;nt<8;++nt){
            bh8 bb = *(const bh8*)&Bs[((w*8+nt)*4 + quad)*128 + c*8];
            zacc[nt] = MFMA16(a, bb, zacc[nt]);
        }
    }
    // store z in A-frag order for phase C
    #pragma unroll
    for (int nt=0;nt<8;++nt)
        #pragma unroll
        for (int reg=0;reg<4;++reg){
            int q = quad*4+reg;
            int col = w*128 + nt*16 + c;
            zsf[(col>>5)*512 + (((col>>3)&3)*16 + q)*8 + (col&7)] = bf16r(zacc[nt][reg]);
        }
    __syncthreads();

    // ---- Phase C: attn = z @ wv  (K=512, 16 steps), + bv + x residual + LN
    f4 cacc[8];
    #pragma unroll
    for (int nt=0;nt<8;++nt) cacc[nt] = (f4){0.f,0.f,0.f,0.f};
    for (int s=0;s<16;++s){
        if (s) __syncthreads();
        #pragma unroll
        for (int i=0;i<8;++i){
            int ch = w*8 + i;
            glds16((const char*)wv_p + (size_t)s*32768 + ch*1024 + lane*16, (char*)Bs + ch*1024);
        }
        __syncthreads();
        bh8 a = *(const bh8*)&zsf[s*512 + (quad*16+c)*8];
        #pragma unroll
        for (int nt=0;nt<8;++nt){
            bh8 bb = *(const bh8*)&Bs[((w*8+nt)*4 + quad)*128 + c*8];
            cacc[nt] = MFMA16(a, bb, cacc[nt]);
        }
    }
    float sv[4] = {0.f,0.f,0.f,0.f}, qv2[4] = {0.f,0.f,0.f,0.f};
    #pragma unroll
    for (int nt=0;nt<8;++nt){
        int col = w*128 + nt*16 + c;
        float bvv = bv[col];
        #pragma unroll
        for (int reg=0;reg<4;++reg){
            int row = rowbase + quad*4 + reg;
            float val = cacc[nt][reg] + bvv + x[(size_t)row*512 + col];
            cacc[nt][reg] = val;
            sv[reg] += val; qv2[reg] = fmaf(val,val,qv2[reg]);
        }
    }
    #pragma unroll
    for (int reg=0;reg<4;++reg){
        float s1=sv[reg], s2=qv2[reg];
        s1 += __shfl_xor(s1,1,64); s2 += __shfl_xor(s2,1,64);
        s1 += __shfl_xor(s1,2,64); s2 += __shfl_xor(s2,2,64);
        s1 += __shfl_xor(s1,4,64); s2 += __shfl_xor(s2,4,64);
        s1 += __shfl_xor(s1,8,64); s2 += __shfl_xor(s2,8,64);
        sv[reg]=s1; qv2[reg]=s2;
    }
    if (c==0){
        #pragma unroll
        for (int reg=0;reg<4;++reg){ redA[w][quad*4+reg]=sv[reg]; redB[w][quad*4+reg]=qv2[reg]; }
    }
    __syncthreads();
    float mean[4], rstd[4];
    #pragma unroll
    for (int reg=0;reg<4;++reg){
        int q = quad*4+reg;
        float S  = redA[0][q]+redA[1][q]+redA[2][q]+redA[3][q];
        float Q2 = redB[0][q]+redB[1][q]+redB[2][q]+redB[3][q];
        float m = S*(1.f/512.f);
        float var = Q2*(1.f/512.f) - m*m;
        mean[reg]=m; rstd[reg]=rsqrtf(var + LN_EPS);
    }
    #pragma unroll
    for (int nt=0;nt<8;++nt){
        int col = w*128 + nt*16 + c;
        float gg = g1[col], bb1 = b1[col];
        #pragma unroll
        for (int reg=0;reg<4;++reg){
            int row = rowbase + quad*4 + reg;
            Y1[(size_t)row*512 + col] = (cacc[nt][reg]-mean[reg])*rstd[reg]*gg + bb1;
        }
    }
}

// ---------------- K4: y2 = LN(relu(y1@wm+bm)+y1), in-place on d_out ----------------
__global__ __launch_bounds__(256) void k4_mlp_ln(
    float* __restrict__ io, const u16* __restrict__ wm_p, const float* __restrict__ bm,
    const float* __restrict__ g2, const float* __restrict__ b2)
{
    __shared__ u16 Asf[512];
    __shared__ u16 Bs[16384];
    __shared__ float redA[4][16], redB[4][16];
    const int t = threadIdx.x, w = t>>6, lane = t&63, quad = lane>>4, c = lane&15;
    const int rowbase = blockIdx.x << 4;
    f4 acc[8];
    #pragma unroll
    for (int nt=0;nt<8;++nt) acc[nt] = (f4){0.f,0.f,0.f,0.f};
    for (int s=0;s<16;++s){
        if (s) __syncthreads();
        if (t < 128){
            int fr = t>>3, fc = t&7;
            float4 yv = *(const float4*)&io[(size_t)(rowbase+fr)*512 + s*32 + fc*4];
            uint2 pkv; pkv.x = pk2(yv.x,yv.y); pkv.y = pk2(yv.z,yv.w);
            *(uint2*)&Asf[((fc>>1)*16 + fr)*8 + (fc&1)*4] = pkv;
        }
        #pragma unroll
        for (int i=0;i<8;++i){
            int ch = w*8 + i;
            glds16((const char*)wm_p + (size_t)s*32768 + ch*1024 + lane*16, (char*)Bs + ch*1024);
        }
        __syncthreads();
        bh8 a = *(const bh8*)&Asf[(quad*16+c)*8];
        #pragma unroll
        for (int nt=0;nt<8;++nt){
            bh8 bb = *(const bh8*)&Bs[((w*8+nt)*4 + quad)*128 + c*8];
            acc[nt] = MFMA16(a, bb, acc[nt]);
        }
    }
    float sv[4] = {0.f,0.f,0.f,0.f}, qv2[4] = {0.f,0.f,0.f,0.f};
    #pragma unroll
    for (int nt=0;nt<8;++nt){
        int col = w*128 + nt*16 + c;
        float bmv = bm[col];
        #pragma unroll
        for (int reg=0;reg<4;++reg){
            int row = rowbase + quad*4 + reg;
            float h = fmaxf(acc[nt][reg]+bmv, 0.f) + io[(size_t)row*512 + col];
            acc[nt][reg] = h;
            sv[reg] += h; qv2[reg] = fmaf(h,h,qv2[reg]);
        }
    }
    #pragma unroll
    for (int reg=0;reg<4;++reg){
        float s1=sv[reg], s2=qv2[reg];
        s1 += __shfl_xor(s1,1,64); s2 += __shfl_xor(s2,1,64);
        s1 += __shfl_xor(s1,2,64); s2 += __shfl_xor(s2,2,64);
        s1 += __shfl_xor(s1,4,64); s2 += __shfl_xor(s2,4,64);
        s1 += __shfl_xor(s1,8,64); s2 += __shfl_xor(s2,8,64);
        sv[reg]=s1; qv2[reg]=s2;
    }
    if (c==0){
        #pragma unroll
        for (int reg=0;reg<4;++reg){ redA[w][quad*4+reg]=sv[reg]; redB[w][quad*4+reg]=qv2[reg]; }
    }
    __syncthreads();
    float mean[4], rstd[4];
    #pragma unroll
    for (int reg=0;reg<4;++reg){
        int q = quad*4+reg;
        float S  = redA[0][q]+redA[1][q]+redA[2][q]+redA[3][q];
        float Q2 = redB[0][q]+redB[1][q]+redB[2][q]+redB[3][q];
        float m = S*(1.f/512.f);
        float var = Q2*(1.f/512.f) - m*m;
        mean[reg]=m; rstd[reg]=rsqrtf(var + LN_EPS);
    }
    #pragma unroll
    for (int nt=0;nt<8;++nt){
        int col = w*128 + nt*16 + c;
        float gg = g2[col], bb2 = b2[col];
        #pragma unroll
        for (int reg=0;reg<4;++reg){
            int row = rowbase + quad*4 + reg;
            io[(size_t)row*512 + col] = (acc[nt][reg]-mean[reg])*rstd[reg]*gg + bb2;
        }
    }
}

extern "C" void kernel_launch(void* const* d_in, const int* in_sizes, int n_in,
                              void* d_out, int out_size, void* d_ws, size_t ws_size,
                              hipStream_t stream) {
    (void)in_sizes; (void)n_in; (void)out_size; (void)ws_size;
    const float* x  = (const float*)d_in[0];
    const float* wq = (const float*)d_in[1];
    const float* bq = (const float*)d_in[2];
    const float* wk = (const float*)d_in[3];
    const float* bk = (const float*)d_in[4];
    const float* wv = (const float*)d_in[5];
    const float* bv = (const float*)d_in[6];
    const float* wm = (const float*)d_in[7];
    const float* bm = (const float*)d_in[8];
    const float* g1 = (const float*)d_in[9];
    const float* b1 = (const float*)d_in[10];
    const float* g2 = (const float*)d_in[11];
    const float* b2 = (const float*)d_in[12];

    // ws layout (11.1 MB): bf16 frag-ordered panels + Q/K frags
    u16* x_pB  = (u16*)d_ws;               // 32 bd x 8 s x 16384 u16 = 8 MB
    u16* wv_p  = x_pB + (size_t)4194304;   // 16 s x 16384 = 512 KB
    u16* wm_p  = wv_p + 262144;            // 512 KB
    u16* wqk_p = wm_p + 262144;            // 16 s x 4096 = 128 KB
    u16* Qb    = wqk_p + 65536;            // 512 rt x 1024 u16 = 1 MB
    u16* Kb    = Qb + 524288;              // 1 MB
    float* outp = (float*)d_out;

    k0_prep    <<<304, 256, 0, stream>>>(x, wq, wk, wv, wm, x_pB, wv_p, wm_p, wqk_p);
    k1_qk      <<<512, 256, 0, stream>>>(x, bq, bk, wqk_p, Qb, Kb);
    k23_attn_ln<<<512, 256, 0, stream>>>(Qb, Kb, x_pB, wv_p, x, bv, g1, b1, outp);
    k4_mlp_ln  <<<512, 256, 0, stream>>>(outp, wm_p, bm, g2, b2);
}